// Round 5
// baseline (105.632 us; speedup 1.0000x reference)
//
#include <hip/hip_runtime.h>

// u_dot_v: score[e] = dot(feat[src[e]], feat[dst[e]]), D_FEAT = 32.
// Two-phase: (1) convert feat fp32 -> bf16 (RNE) into d_ws: rows shrink
// 128 B -> 64 B, halving gathered bytes and making the table (32 MB) fit
// aggregate L2. (2) per-edge gather-dot on bf16 rows, fp32 accumulate.
// Tolerance: harness threshold 0.68 (bf16 floor); bf16 input rounding adds
// <= ~0.14 worst case on |score|<=34.
// Falls back to the proven fp32 kernel if ws_size < 32 MB.

#define D_FEAT 32

typedef float          v4f __attribute__((ext_vector_type(4)));
typedef int            v4i __attribute__((ext_vector_type(4)));
typedef unsigned short v8u __attribute__((ext_vector_type(8)));

__device__ inline unsigned short f2bf(float f) {
    unsigned u = __builtin_bit_cast(unsigned, f);
    unsigned r = u + 0x7FFFu + ((u >> 16) & 1u);   // round-to-nearest-even
    return (unsigned short)(r >> 16);
}
__device__ inline float bf2f(unsigned short h) {
    return __builtin_bit_cast(float, (unsigned)h << 16);
}

// ---- Phase 1: feat fp32 -> bf16 into workspace (streaming, nontemporal) ----
__global__ __launch_bounds__(256) void convert_bf16_kernel(
    const float* __restrict__ feat,
    unsigned short* __restrict__ fb,
    int n)   // total elements (N_NODES * D_FEAT)
{
    const int tid    = blockIdx.x * blockDim.x + threadIdx.x;
    const int stride = gridDim.x * blockDim.x;
    const int nvec   = n >> 3;                      // 8 elements per thread-iter

    for (int j = tid; j < nvec; j += stride) {
        const v4f x0 = __builtin_nontemporal_load(reinterpret_cast<const v4f*>(feat + (size_t)j * 8));
        const v4f x1 = __builtin_nontemporal_load(reinterpret_cast<const v4f*>(feat + (size_t)j * 8 + 4));
        v8u r;
        r[0] = f2bf(x0.x); r[1] = f2bf(x0.y); r[2] = f2bf(x0.z); r[3] = f2bf(x0.w);
        r[4] = f2bf(x1.x); r[5] = f2bf(x1.y); r[6] = f2bf(x1.z); r[7] = f2bf(x1.w);
        __builtin_nontemporal_store(r, reinterpret_cast<v8u*>(fb + (size_t)j * 8));
    }
    // scalar tail
    for (int k = (nvec << 3) + tid; k < n; k += stride) {
        fb[k] = f2bf(feat[k]);
    }
}

// ---- Phase 2: per-edge dot on bf16 rows (64 B/row, 4 lanes/edge) ----
__global__ __launch_bounds__(256) void edge_dot_bf16_kernel(
    const unsigned short* __restrict__ fb,
    const int*   __restrict__ src,
    const int*   __restrict__ dst,
    float*       __restrict__ out,
    int n_edges)
{
    const int lane4 = threadIdx.x & 3;
    const int off   = lane4 * 8;                    // 8 bf16 elements per lane
    const int gid   = (blockIdx.x * blockDim.x + threadIdx.x) >> 2;
    const int nquads = n_edges >> 2;

    if (gid < nquads) {
        const int e = gid * 4;
        const v4i s4 = __builtin_nontemporal_load(reinterpret_cast<const v4i*>(src + e));
        const v4i d4 = __builtin_nontemporal_load(reinterpret_cast<const v4i*>(dst + e));

        const v8u a0 = *reinterpret_cast<const v8u*>(fb + (size_t)s4.x * D_FEAT + off);
        const v8u a1 = *reinterpret_cast<const v8u*>(fb + (size_t)s4.y * D_FEAT + off);
        const v8u a2 = *reinterpret_cast<const v8u*>(fb + (size_t)s4.z * D_FEAT + off);
        const v8u a3 = *reinterpret_cast<const v8u*>(fb + (size_t)s4.w * D_FEAT + off);
        const v8u b0 = *reinterpret_cast<const v8u*>(fb + (size_t)d4.x * D_FEAT + off);
        const v8u b1 = *reinterpret_cast<const v8u*>(fb + (size_t)d4.y * D_FEAT + off);
        const v8u b2 = *reinterpret_cast<const v8u*>(fb + (size_t)d4.z * D_FEAT + off);
        const v8u b3 = *reinterpret_cast<const v8u*>(fb + (size_t)d4.w * D_FEAT + off);

        float p0 = 0.f, p1 = 0.f, p2 = 0.f, p3 = 0.f;
#pragma unroll
        for (int k = 0; k < 8; ++k) {
            p0 += bf2f(a0[k]) * bf2f(b0[k]);
            p1 += bf2f(a1[k]) * bf2f(b1[k]);
            p2 += bf2f(a2[k]) * bf2f(b2[k]);
            p3 += bf2f(a3[k]) * bf2f(b3[k]);
        }

        p0 += __shfl_xor(p0, 1, 4);
        p1 += __shfl_xor(p1, 1, 4);
        p2 += __shfl_xor(p2, 1, 4);
        p3 += __shfl_xor(p3, 1, 4);
        p0 += __shfl_xor(p0, 2, 4);
        p1 += __shfl_xor(p1, 2, 4);
        p2 += __shfl_xor(p2, 2, 4);
        p3 += __shfl_xor(p3, 2, 4);

        if (lane4 == 0) {
            v4f r; r.x = p0; r.y = p1; r.z = p2; r.w = p3;
            __builtin_nontemporal_store(r, reinterpret_cast<v4f*>(out + e));
        }
    } else if (gid == nquads) {
        for (int e = nquads * 4; e < n_edges; ++e) {
            const int s = src[e];
            const int d = dst[e];
            const v8u a = *reinterpret_cast<const v8u*>(fb + (size_t)s * D_FEAT + off);
            const v8u b = *reinterpret_cast<const v8u*>(fb + (size_t)d * D_FEAT + off);
            float p = 0.f;
#pragma unroll
            for (int k = 0; k < 8; ++k) p += bf2f(a[k]) * bf2f(b[k]);
            p += __shfl_xor(p, 1, 4);
            p += __shfl_xor(p, 2, 4);
            if (lane4 == 0) out[e] = p;
        }
    }
}

// ---- Fallback: proven fp32 path (R4 kernel) if workspace is too small ----
__global__ __launch_bounds__(256) void edge_dot_f32_kernel(
    const float* __restrict__ feat,
    const int*   __restrict__ src,
    const int*   __restrict__ dst,
    float*       __restrict__ out,
    int n_edges)
{
    const int lane8 = threadIdx.x & 7;
    const int off   = lane8 * 4;
    const int gid   = (blockIdx.x * blockDim.x + threadIdx.x) >> 3;
    const int nquads = n_edges >> 2;

    if (gid < nquads) {
        const int e = gid * 4;
        const v4i s4 = __builtin_nontemporal_load(reinterpret_cast<const v4i*>(src + e));
        const v4i d4 = __builtin_nontemporal_load(reinterpret_cast<const v4i*>(dst + e));
        const v4f a0 = *reinterpret_cast<const v4f*>(feat + (size_t)s4.x * D_FEAT + off);
        const v4f a1 = *reinterpret_cast<const v4f*>(feat + (size_t)s4.y * D_FEAT + off);
        const v4f a2 = *reinterpret_cast<const v4f*>(feat + (size_t)s4.z * D_FEAT + off);
        const v4f a3 = *reinterpret_cast<const v4f*>(feat + (size_t)s4.w * D_FEAT + off);
        const v4f b0 = *reinterpret_cast<const v4f*>(feat + (size_t)d4.x * D_FEAT + off);
        const v4f b1 = *reinterpret_cast<const v4f*>(feat + (size_t)d4.y * D_FEAT + off);
        const v4f b2 = *reinterpret_cast<const v4f*>(feat + (size_t)d4.z * D_FEAT + off);
        const v4f b3 = *reinterpret_cast<const v4f*>(feat + (size_t)d4.w * D_FEAT + off);

        float p0 = a0.x*b0.x + a0.y*b0.y + a0.z*b0.z + a0.w*b0.w;
        float p1 = a1.x*b1.x + a1.y*b1.y + a1.z*b1.z + a1.w*b1.w;
        float p2 = a2.x*b2.x + a2.y*b2.y + a2.z*b2.z + a2.w*b2.w;
        float p3 = a3.x*b3.x + a3.y*b3.y + a3.z*b3.z + a3.w*b3.w;

        p0 += __shfl_xor(p0, 1, 8); p1 += __shfl_xor(p1, 1, 8);
        p2 += __shfl_xor(p2, 1, 8); p3 += __shfl_xor(p3, 1, 8);
        p0 += __shfl_xor(p0, 2, 8); p1 += __shfl_xor(p1, 2, 8);
        p2 += __shfl_xor(p2, 2, 8); p3 += __shfl_xor(p3, 2, 8);
        p0 += __shfl_xor(p0, 4, 8); p1 += __shfl_xor(p1, 4, 8);
        p2 += __shfl_xor(p2, 4, 8); p3 += __shfl_xor(p3, 4, 8);

        if (lane8 == 0) {
            v4f r; r.x = p0; r.y = p1; r.z = p2; r.w = p3;
            __builtin_nontemporal_store(r, reinterpret_cast<v4f*>(out + e));
        }
    } else if (gid == nquads) {
        for (int e = nquads * 4; e < n_edges; ++e) {
            const int s = src[e];
            const int d = dst[e];
            const v4f a = *reinterpret_cast<const v4f*>(feat + (size_t)s * D_FEAT + off);
            const v4f b = *reinterpret_cast<const v4f*>(feat + (size_t)d * D_FEAT + off);
            float p = a.x*b.x + a.y*b.y + a.z*b.z + a.w*b.w;
            p += __shfl_xor(p, 1, 8);
            p += __shfl_xor(p, 2, 8);
            p += __shfl_xor(p, 4, 8);
            if (lane8 == 0) out[e] = p;
        }
    }
}

extern "C" void kernel_launch(void* const* d_in, const int* in_sizes, int n_in,
                              void* d_out, int out_size, void* d_ws, size_t ws_size,
                              hipStream_t stream) {
    const float* feat = (const float*)d_in[0];
    const int*   src  = (const int*)d_in[1];
    const int*   dst  = (const int*)d_in[2];
    float*       out  = (float*)d_out;
    const int n_feat_elems = in_sizes[0];           // N_NODES * D_FEAT
    const int n_edges      = in_sizes[1];

    const int block = 256;
    const size_t need = (size_t)n_feat_elems * sizeof(unsigned short);

    if (ws_size >= need) {
        unsigned short* fb = (unsigned short*)d_ws;

        // Phase 1: convert (96 MB streaming)
        convert_bf16_kernel<<<2048, block, 0, stream>>>(feat, fb, n_feat_elems);

        // Phase 2: gather-dot, 4 lanes/edge, exact cover
        const int nquads  = n_edges >> 2;
        const int ngroups = nquads + ((n_edges & 3) ? 1 : 0);
        const int grid    = (ngroups * 4 + block - 1) / block;
        edge_dot_bf16_kernel<<<grid, block, 0, stream>>>(fb, src, dst, out, n_edges);
    } else {
        const int nquads  = n_edges >> 2;
        const int ngroups = nquads + ((n_edges & 3) ? 1 : 0);
        const int grid    = (ngroups * 8 + block - 1) / block;
        edge_dot_f32_kernel<<<grid, block, 0, stream>>>(feat, src, dst, out, n_edges);
    }
}

// Round 6
// 95.673 us; speedup vs baseline: 1.1041x; 1.1041x over previous
//
#include <hip/hip_runtime.h>

// u_dot_v: score[e] = dot(feat[src[e]], feat[dst[e]]), D_FEAT = 32 (128 B/row).
// FINAL (reverted to R4 — measured optimum, 95.7 us):
//   8 lanes/edge, quad of edges per 8-lane group, exact-cover grid,
//   nontemporal index/output streams. Each gather instruction touches 8
//   fully-consumed 128 B rows (perfect line utilization).
// Measured: byte-bound at the ~3.4 TB/s random-128B L2-miss/fabric plateau;
// traffic (302 MB) is within ~7% of the compulsory-miss floor. bf16 table
// halves demand but not fills (128 B granule) and the convert pass costs
// more than it saves (R5: 105.6 us). Locality restructurings net ~0 on paper.

#define D_FEAT 32

typedef int   v4i __attribute__((ext_vector_type(4)));
typedef float v4f __attribute__((ext_vector_type(4)));

__global__ __launch_bounds__(256) void edge_dot_nt_kernel(
    const float* __restrict__ feat,
    const int*   __restrict__ src,
    const int*   __restrict__ dst,
    float*       __restrict__ out,
    int n_edges)
{
    const int lane8 = threadIdx.x & 7;
    const int off   = lane8 * 4;
    const int gid   = (blockIdx.x * blockDim.x + threadIdx.x) >> 3;
    const int nquads = n_edges >> 2;

    if (gid < nquads) {
        const int e = gid * 4;
        const v4i s4 = __builtin_nontemporal_load(reinterpret_cast<const v4i*>(src + e));
        const v4i d4 = __builtin_nontemporal_load(reinterpret_cast<const v4i*>(dst + e));

        const v4f a0 = *reinterpret_cast<const v4f*>(feat + (size_t)s4.x * D_FEAT + off);
        const v4f a1 = *reinterpret_cast<const v4f*>(feat + (size_t)s4.y * D_FEAT + off);
        const v4f a2 = *reinterpret_cast<const v4f*>(feat + (size_t)s4.z * D_FEAT + off);
        const v4f a3 = *reinterpret_cast<const v4f*>(feat + (size_t)s4.w * D_FEAT + off);
        const v4f b0 = *reinterpret_cast<const v4f*>(feat + (size_t)d4.x * D_FEAT + off);
        const v4f b1 = *reinterpret_cast<const v4f*>(feat + (size_t)d4.y * D_FEAT + off);
        const v4f b2 = *reinterpret_cast<const v4f*>(feat + (size_t)d4.z * D_FEAT + off);
        const v4f b3 = *reinterpret_cast<const v4f*>(feat + (size_t)d4.w * D_FEAT + off);

        float p0 = a0.x*b0.x + a0.y*b0.y + a0.z*b0.z + a0.w*b0.w;
        float p1 = a1.x*b1.x + a1.y*b1.y + a1.z*b1.z + a1.w*b1.w;
        float p2 = a2.x*b2.x + a2.y*b2.y + a2.z*b2.z + a2.w*b2.w;
        float p3 = a3.x*b3.x + a3.y*b3.y + a3.z*b3.z + a3.w*b3.w;

        p0 += __shfl_xor(p0, 1, 8); p1 += __shfl_xor(p1, 1, 8);
        p2 += __shfl_xor(p2, 1, 8); p3 += __shfl_xor(p3, 1, 8);
        p0 += __shfl_xor(p0, 2, 8); p1 += __shfl_xor(p1, 2, 8);
        p2 += __shfl_xor(p2, 2, 8); p3 += __shfl_xor(p3, 2, 8);
        p0 += __shfl_xor(p0, 4, 8); p1 += __shfl_xor(p1, 4, 8);
        p2 += __shfl_xor(p2, 4, 8); p3 += __shfl_xor(p3, 4, 8);

        if (lane8 == 0) {
            v4f r; r.x = p0; r.y = p1; r.z = p2; r.w = p3;
            __builtin_nontemporal_store(r, reinterpret_cast<v4f*>(out + e));
        }
    } else if (gid == nquads) {
        // tail: up to 3 edges, handled serially by the one extra group
        for (int e = nquads * 4; e < n_edges; ++e) {
            const int s = src[e];
            const int d = dst[e];
            const v4f a = *reinterpret_cast<const v4f*>(feat + (size_t)s * D_FEAT + off);
            const v4f b = *reinterpret_cast<const v4f*>(feat + (size_t)d * D_FEAT + off);
            float p = a.x*b.x + a.y*b.y + a.z*b.z + a.w*b.w;
            p += __shfl_xor(p, 1, 8);
            p += __shfl_xor(p, 2, 8);
            p += __shfl_xor(p, 4, 8);
            if (lane8 == 0) __builtin_nontemporal_store(p, out + e);
        }
    }
}

extern "C" void kernel_launch(void* const* d_in, const int* in_sizes, int n_in,
                              void* d_out, int out_size, void* d_ws, size_t ws_size,
                              hipStream_t stream) {
    const float* feat = (const float*)d_in[0];
    const int*   src  = (const int*)d_in[1];
    const int*   dst  = (const int*)d_in[2];
    float*       out  = (float*)d_out;
    const int n_edges = in_sizes[1];

    const int block = 256;
    const int nquads  = n_edges >> 2;
    const int ngroups = nquads + ((n_edges & 3) ? 1 : 0);   // 8-lane groups needed
    const int grid    = (ngroups * 8 + block - 1) / block;  // exact cover

    edge_dot_nt_kernel<<<grid, block, 0, stream>>>(feat, src, dst, out, n_edges);
}